// Round 14
// baseline (247.992 us; speedup 1.0000x reference)
//
#include <hip/hip_runtime.h>
#include <hip/hip_bf16.h>

#define NN 2000
#define NE 8192
#define DIM 10000
#define NCLS 10
#define HASH_SZ 32768
#define WORDS 313          // ceil(10000/32) packed sign words per node
#define ECH 8              // edge-chunk split for encpop grid.y
#define RBLK 64            // i-rows per rank block
#define REGD 12            // register-hoisted CSR entries per node (fallback loop beyond)
#define DUMMY 2047         // wv[DUMMY] == +0.0f always
#define NTILE (WORDS * ECH)               // 2504 encpop tiles

// ---- workspace layout (byte offsets) ----
#define WS_K       0                      // int        (distinct-edge counter)
#define WS_DONE    8                      // u32        (encpop completion counter)
#define WS_ENC     64                     // int[10016] per-dim xor-bit counts
#define WS_V       328576                 // f32[2000]  pagerank result
#define WS_RANK    336576                 // int[2000]  stable rank of each node
#define WS_PAIRS   344576                 // u32[8192]  packed (a<<16)|b node-id pairs per distinct edge
#define WS_HASH    377344                 // int[32768] hash set
#define WS_PACK    508416                 // u32[313*2000] packed sign bits, layout [word][node]

#define ZERO_BYTES 40128                  // [0, 40128): K + DONE + ENC counts
#define ZERO_VEC  (ZERO_BYTES / 16)       // 2508 uint4 zero stores
#define HASH_VEC  (HASH_SZ * 4 / 16)      // 8192 uint4 0xFF stores
#define INIT_TOT  (ZERO_VEC + HASH_VEC)   // 10700
#define FUSE_ITEMS (INIT_TOT + NN * WORDS)        // 636700 work items in blocks 1+
#define FUSE_BLK  ((FUSE_ITEMS + 1023) / 1024)    // 622

// DPP wave64 sum: canonical gfx9 sequence; lane 63 ends with the full wave sum.
// Only used for the err gate (~5 orders of magnitude of tolerance at 0.002).
__device__ __forceinline__ float wave_sum_dpp(float x) {
#define DPPADD(ctrl, rm, bm)                                                     \
  {                                                                              \
    int y_ = __builtin_amdgcn_update_dpp(0, __float_as_int(x), ctrl, rm, bm, false); \
    x = __fadd_rn(x, __int_as_float(y_));                                        \
  }
  DPPADD(0x111, 0xF, 0xF);  // row_shr:1
  DPPADD(0x112, 0xF, 0xF);  // row_shr:2
  DPPADD(0x114, 0xF, 0xE);  // row_shr:4
  DPPADD(0x118, 0xF, 0xC);  // row_shr:8
  DPPADD(0x142, 0xA, 0xF);  // row_bcast:15 -> rows 1,3
  DPPADD(0x143, 0xC, 0xF);  // row_bcast:31 -> rows 2,3
#undef DPPADD
  return x;                  // valid in lane 63
}

// ---------- K1: block 0 = build + pagerank (4 rows/thread, waves 0-7 active);
//            blocks 1+ = workspace init + sign-bit pack (concurrent) ----------
__global__ __launch_bounds__(1024) void fused_pre_kernel(const int* __restrict__ eidx,
                                                         const float* __restrict__ W,
                                                         char* __restrict__ ws) {
  if (blockIdx.x != 0) {
    // ---- init + pack, 1024 threads/block ----
    int t = (int)(blockIdx.x - 1) * 1024 + threadIdx.x;
    if (t < ZERO_VEC) {
      reinterpret_cast<uint4*>(ws)[t] = make_uint4(0u, 0u, 0u, 0u);
      return;
    }
    if (t < INIT_TOT) {
      reinterpret_cast<uint4*>(ws + WS_HASH)[t - ZERO_VEC] =
          make_uint4(0xFFFFFFFFu, 0xFFFFFFFFu, 0xFFFFFFFFu, 0xFFFFFFFFu);
      return;
    }
    int j = t - INIT_TOT;
    if (j >= NN * WORDS) return;
    unsigned int* packed = (unsigned int*)(ws + WS_PACK);
    int w = j / NN;
    int node = j - w * NN;             // consecutive threads -> consecutive nodes, same word
    int d0 = w * 32;
    const float* p = W + (size_t)node * DIM + d0;   // 128B-aligned per-lane chunk
    unsigned int m = 0;
    if (d0 + 32 <= DIM) {
#pragma unroll
      for (int q = 0; q < 8; ++q) {
        float4 v4 = *reinterpret_cast<const float4*>(p + q * 4);
        m |= (__float_as_uint(v4.x) >> 31) << (q * 4);
        m |= (__float_as_uint(v4.y) >> 31) << (q * 4 + 1);
        m |= (__float_as_uint(v4.z) >> 31) << (q * 4 + 2);
        m |= (__float_as_uint(v4.w) >> 31) << (q * 4 + 3);
      }
    } else {
      for (int q = 0; q < DIM - d0; ++q) m |= (__float_as_uint(p[q]) >> 31) << q;
    }
    packed[(size_t)w * NN + node] = m; // coalesced
    return;
  }

  // ---- block 0: build + pagerank ----
  __shared__ unsigned short s_ccol[NE];   // 16 KB  CSR col values
  __shared__ unsigned short s_ced[NE];    // 16 KB  edge ids during build
  __shared__ int s_base[NN + 1];          // 8 KB   CSR row starts
  __shared__ int s_aux[2048];             // degc -> val (f32 alias, in-place)
  __shared__ int s_w[2048];               // rowcnt/scan -> fill counters
  __shared__ float s_wv[2][2048];         // 16 KB  double-buffered val[c]*v[c]
  __shared__ float4 s_red4[2][4];         // err partials (waves 8-15 contribute 0)
  float* s_redf = (float*)s_red4;
  float* s_val = (float*)s_aux;

  int tid = threadIdx.x;
  int wid = tid >> 6, lane = tid & 63;

  for (int i = tid; i < 2048; i += 1024) { s_w[i] = 0; s_aux[i] = 0; }
  for (int i = NN + tid; i < 2048; i += 1024) { s_wv[0][i] = 0.f; s_wv[1][i] = 0.f; }
  __syncthreads();

  // --- count: row counts (s_w) + col in-degree (s_aux) ---
  int er[8], ec[8];
#pragma unroll
  for (int k = 0; k < 8; ++k) {
    int e = tid + k * 1024;
    er[k] = eidx[e];
    ec[k] = eidx[NE + e];
    atomicAdd(&s_w[er[k]], 1);
    atomicAdd(&s_aux[ec[k]], 1);
  }
  __syncthreads();

  // --- inclusive scan of row counts -> base ---
  {
    int n0 = tid, n1 = tid + 1024;
    for (int st = 1; st < 2048; st <<= 1) {
      int v0 = (n0 >= st) ? s_w[n0 - st] : 0;
      int v1 = (n1 >= st) ? s_w[n1 - st] : 0;
      __syncthreads();
      s_w[n0] += v0;
      s_w[n1] += v1;
      __syncthreads();
    }
    if (tid == 0) s_base[0] = 0;
    for (int n = tid; n < NN; n += 1024) s_base[n + 1] = s_w[n];
  }
  __syncthreads();
  for (int i = tid; i < 2048; i += 1024) s_w[i] = 0;   // reuse as fill counters
  __syncthreads();

  // --- fill (atomic, unordered) keeping edge id ---
#pragma unroll
  for (int k = 0; k < 8; ++k) {
    int e = tid + k * 1024;
    int r = er[k];
    int slot = s_base[r] + atomicAdd(&s_w[r], 1);
    s_ccol[slot] = (unsigned short)ec[k];
    s_ced[slot] = (unsigned short)e;
  }
  __syncthreads();

  // --- per-node insertion sort by edge id (stable CSR) + val + wv[0] init ---
  const float p = 0.0005f;              // f32(1.0/2000)
  const float addv = 0.0005f * 0.15f;   // p * f32(1.0-0.85)
  for (int n = tid; n < NN; n += 1024) {
    int s0 = s_base[n], s1 = s_base[n + 1];
    for (int a = s0 + 1; a < s1; ++a) {
      unsigned short ke = s_ced[a], kc = s_ccol[a];
      int b = a - 1;
      while (b >= s0 && s_ced[b] > ke) {
        s_ced[b + 1] = s_ced[b];
        s_ccol[b + 1] = s_ccol[b];
        --b;
      }
      s_ced[b + 1] = ke;
      s_ccol[b + 1] = kc;
    }
    float vv = 0.85f / (float)s_aux[n];   // inf if deg==0: never gathered
    s_val[n] = vv;                        // in-place alias of s_aux[n]
    s_wv[0][n] = __fmul_rn(vv, p);
  }
  __syncthreads();

  // --- hoist per-thread constants: 4 rows/thread for tid<512 (waves 0-7) ---
  // Same per-row arithmetic as before; only row->thread mapping changes, which
  // affects only err's lane pairing (tolerated by the 0.002 gate margin).
  bool own = (tid < 512);
  int r0 = tid, r1 = tid + 512, r2 = tid + 1024, r3 = tid + 1536;
  bool has3 = own && (r3 < NN);
  int b0s = 0, b0e = 0, b1s = 0, b1e = 0, b2s = 0, b2e = 0, b3s = 0, b3e = 0;
  float val0 = 0.f, val1 = 0.f, val2 = 0.f, val3 = 0.f;
  if (own) {
    b0s = s_base[r0]; b0e = s_base[r0 + 1];
    b1s = s_base[r1]; b1e = s_base[r1 + 1];
    b2s = s_base[r2]; b2e = s_base[r2 + 1];
    val0 = s_val[r0]; val1 = s_val[r1]; val2 = s_val[r2];
    if (has3) { b3s = s_base[r3]; b3e = s_base[r3 + 1]; val3 = s_val[r3]; }
  }
  int c0r[REGD], c1r[REGD], c2r[REGD], c3r[REGD];
#pragma unroll
  for (int k = 0; k < REGD; ++k) {
    c0r[k] = (own && b0s + k < b0e) ? (int)s_ccol[min(b0s + k, NE - 1)] : DUMMY;
    c1r[k] = (own && b1s + k < b1e) ? (int)s_ccol[min(b1s + k, NE - 1)] : DUMMY;
    c2r[k] = (own && b2s + k < b2e) ? (int)s_ccol[min(b2s + k, NE - 1)] : DUMMY;
    c3r[k] = (has3 && b3s + k < b3e) ? (int)s_ccol[min(b3s + k, NE - 1)] : DUMMY;
  }
  float vc0 = p, vc1 = p, vc2 = p, vc3 = p;

#define ROW_SUM(CR, BS, BE, VC, VN)                                            \
  {                                                                            \
    float sum = 0.f;                                                           \
    _Pragma("unroll")                                                          \
    for (int k = 0; k < REGD; ++k) sum = __fadd_rn(sum, wv[CR[k]]);            \
    for (int k = (BS) + REGD; k < (BE); ++k) sum = __fadd_rn(sum, wv[s_ccol[k]]); \
    VN = __fadd_rn(sum, addv);                                                 \
  }

  float err = __builtin_inff();
  int it = 0;
  int pb = 0;
  while (it < 100 && err >= 0.002f) {
    const float* wv = s_wv[pb];
    float ep = 0.f;
    float vn0 = vc0, vn1 = vc1, vn2 = vc2, vn3 = vc3;
    if (own) {
      ROW_SUM(c0r, b0s, b0e, vc0, vn0); ep += fabsf(__fsub_rn(vn0, vc0));
      ROW_SUM(c1r, b1s, b1e, vc1, vn1); ep += fabsf(__fsub_rn(vn1, vc1));
      ROW_SUM(c2r, b2s, b2e, vc2, vn2); ep += fabsf(__fsub_rn(vn2, vc2));
      if (has3) { ROW_SUM(c3r, b3s, b3e, vc3, vn3); ep += fabsf(__fsub_rn(vn3, vc3)); }
      float* wvn = s_wv[pb ^ 1];         // safe: gathers read s_wv[pb]
      wvn[r0] = __fmul_rn(val0, vn0);
      wvn[r1] = __fmul_rn(val1, vn1);
      wvn[r2] = __fmul_rn(val2, vn2);
      if (has3) wvn[r3] = __fmul_rn(val3, vn3);
    }
    vc0 = vn0; vc1 = vn1; vc2 = vn2; vc3 = vn3;
    float wsum = wave_sum_dpp(ep);       // waves 8-15: exact 0
    if (lane == 63) s_redf[pb * 16 + wid] = wsum;
    __syncthreads();            // wv[pb^1] + s_red[pb] visible; wv[pb] reads done
    float4 q0 = s_red4[pb][0], q1 = s_red4[pb][1], q2 = s_red4[pb][2], q3 = s_red4[pb][3];
    float t = 0.f;
    t += q0.x; t += q0.y; t += q0.z; t += q0.w;
    t += q1.x; t += q1.y; t += q1.z; t += q1.w;
    t += q2.x; t += q2.y; t += q2.z; t += q2.w;   // +0 entries: exact
    t += q3.x; t += q3.y; t += q3.z; t += q3.w;
    err = t;
    pb ^= 1;
    ++it;
  }
#undef ROW_SUM
  float* vout = (float*)(ws + WS_V);
  if (own) {
    vout[r0] = vc0;
    vout[r1] = vc1;
    vout[r2] = vc2;
    if (has3) vout[r3] = vc3;
  }
}

// ---------- K2: blocks 0..31 stable rank; blocks 32..63 dedup (independent) ----------
__global__ __launch_bounds__(256) void rank_dedup_kernel(const int* __restrict__ eidx,
                                                         char* __restrict__ ws) {
  int tid = threadIdx.x;
  if (blockIdx.x < 32) {
    // --- stable rank: LDS-staged, 4-way j-split ---
    const float* v = (const float*)(ws + WS_V);
    int* rnk = (int*)(ws + WS_RANK);
    __shared__ float s_v[NN];
    __shared__ int s_part[4][RBLK];
    for (int j = tid; j < NN; j += 256) s_v[j] = v[j];
    __syncthreads();
    int li = tid & (RBLK - 1);
    int seg = tid >> 6;                  // 0..3
    int i = blockIdx.x * RBLK + li;
    float vi = (i < NN) ? s_v[i] : 0.f;
    const int jper = NN / 4;             // 500
    int j0 = seg * jper, j1 = j0 + jper;
    int r = 0;
    for (int j = j0; j < j1; ++j) {
      float vj = s_v[j];                 // broadcast: conflict-free
      r += ((vj < vi) || (vj == vi && j < i)) ? 1 : 0;
    }
    s_part[seg][li] = r;
    __syncthreads();
    if (tid < RBLK) {
      int i2 = blockIdx.x * RBLK + tid;
      if (i2 < NN)
        rnk[i2] = s_part[0][tid] + s_part[1][tid] + s_part[2][tid] + s_part[3][tid];
    }
  } else {
    // --- dedup via hash set; pairs carry NODE IDS (rank translation in encpop) ---
    int* hash = (int*)(ws + WS_HASH);
    unsigned int* pairs = (unsigned int*)(ws + WS_PAIRS);
    int* Kp = (int*)(ws + WS_K);
    int e = (int)(blockIdx.x - 32) * 256 + tid;
    int r = eidx[e], c = eidx[NE + e];
    int a = min(r, c), b = max(r, c);
    int key = a * NN + b;
    unsigned int h = ((unsigned int)key * 2654435761u) >> 17;
    for (;;) {
      h &= (HASH_SZ - 1);
      int old = atomicCAS(&hash[h], -1, key);
      if (old == -1) {                   // this edge owns the distinct key
        int idx = atomicAdd(Kp, 1);
        pairs[idx] = ((unsigned int)a << 16) | (unsigned int)b;
        return;
      }
      if (old == key) return;            // duplicate
      ++h;
    }
  }
}

// ---------- K3: per-dim xor-bit counts; LAST finishing block computes out ----------
__global__ __launch_bounds__(256) void encpop_kernel(const float* __restrict__ Wc,
                                                     char* __restrict__ ws,
                                                     float* __restrict__ out) {
  const unsigned int* packed = (const unsigned int*)(ws + WS_PACK);
  const unsigned int* pairs = (const unsigned int*)(ws + WS_PAIRS);
  const int* Kp = (const int*)(ws + WS_K);
  const int* rnk_g = (const int*)(ws + WS_RANK);
  int* enc_int = (int*)(ws + WS_ENC);
  unsigned int* done = (unsigned int*)(ws + WS_DONE);
  __shared__ unsigned short s_rnk[NN]; // node -> rank
  __shared__ unsigned int s_col[NN];   // node -> this word's bits of W-row rank[node]
  __shared__ int s_part[4][32];
  __shared__ int s_last;
  int w = blockIdx.x;
  int tid = threadIdx.x;
  int wid = tid >> 6, lane = tid & 63;
  for (int i = tid; i < NN; i += 256) s_rnk[i] = (unsigned short)rnk_g[i];
  __syncthreads();
  for (int i = tid; i < NN; i += 256)
    s_col[i] = packed[(size_t)w * NN + s_rnk[i]];   // L2-resident gather
  __syncthreads();
  int K = *Kp;
  const int per = NE / ECH;            // 1024
  int e0 = blockIdx.y * per;
  int cnt[32];
#pragma unroll
  for (int b = 0; b < 32; ++b) cnt[b] = 0;
  for (int e = e0 + tid; e < e0 + per; e += 256) {   // uniform trip count: ballot-safe
    unsigned int x = 0;
    if (e < K) {
      unsigned int pk = pairs[e];
      x = s_col[pk >> 16] ^ s_col[pk & 0xffffu];
    }
#pragma unroll
    for (int b = 0; b < 32; ++b)
      cnt[b] += (int)__popcll(__ballot(x & (1u << b)));   // uniform per wave
  }
  if (lane == 0) {
#pragma unroll
    for (int b = 0; b < 32; ++b) s_part[wid][b] = cnt[b];
  }
  __syncthreads();
  if (tid < 32) {
    int tot = s_part[0][tid] + s_part[1][tid] + s_part[2][tid] + s_part[3][tid];
    if (tot) atomicAdd(&enc_int[w * 32 + tid], tot);   // exact integer accumulation
  }
  // ---- completion protocol: last block computes out (canonical last-block) ----
  __syncthreads();                       // all this block's atomicAdds issued
  if (tid == 0) {
    __threadfence();                     // release our enc updates
    unsigned int prev = __hip_atomic_fetch_add(done, 1u, __ATOMIC_ACQ_REL,
                                               __HIP_MEMORY_SCOPE_AGENT);
    s_last = (prev == (unsigned int)(NTILE - 1)) ? 1 : 0;
  }
  __syncthreads();
  if (!s_last) return;
  __threadfence();                       // acquire all blocks' enc updates
  // out[c] = sum_d (K - 2*cnt[d]) * Wc[c][d]  -- same add order as old out_kernel
  __shared__ float red[4];
  for (int c = 0; c < NCLS; ++c) {
    float s = 0.f;
    for (int d = tid; d < DIM; d += 256) {
      int cd = __hip_atomic_load(&enc_int[d], __ATOMIC_RELAXED, __HIP_MEMORY_SCOPE_AGENT);
      s += (float)(K - 2 * cd) * Wc[c * DIM + d];
    }
    for (int o = 32; o > 0; o >>= 1) s += __shfl_down(s, o, 64);
    if ((tid & 63) == 0) red[tid >> 6] = s;
    __syncthreads();
    if (tid == 0) out[c] = red[0] + red[1] + red[2] + red[3];
    __syncthreads();
  }
}

extern "C" void kernel_launch(void* const* d_in, const int* in_sizes, int n_in,
                              void* d_out, int out_size, void* d_ws, size_t ws_size,
                              hipStream_t stream) {
  const int* eidx = (const int*)d_in[0];        // edge_index int32 [2, 8192]
  const float* Wn = (const float*)d_in[1];      // node_ids_weight f32 [2000, 10000]
  const float* Wc = (const float*)d_in[2];      // classify_weight f32 [10, 10000]
  float* out = (float*)d_out;
  char* ws = (char*)d_ws;

  fused_pre_kernel<<<FUSE_BLK + 1, 1024, 0, stream>>>(eidx, Wn, ws);
  rank_dedup_kernel<<<64, 256, 0, stream>>>(eidx, ws);
  encpop_kernel<<<dim3(WORDS, ECH), 256, 0, stream>>>(Wc, ws, out);
}

// Round 15
// 83.953 us; speedup vs baseline: 2.9539x; 2.9539x over previous
//
#include <hip/hip_runtime.h>
#include <hip/hip_bf16.h>

#define NN 2000
#define NE 8192
#define DIM 10000
#define NCLS 10
#define HASH_SZ 32768
#define WORDS 313          // ceil(10000/32) packed sign words per node
#define ECH 8              // edge-chunk split for encpop grid.y
#define RBLK 64            // i-rows per rank block
#define REGD 12            // register-hoisted CSR entries per node (fallback loop beyond)
#define DUMMY 2047         // wv[DUMMY] == +0.0f always

// ---- workspace layout (byte offsets) ----
#define WS_K       0                      // int        (distinct-edge counter)
#define WS_ENC     64                     // int[10016] per-dim xor-bit counts
#define WS_V       328576                 // f32[2000]  pagerank result
#define WS_RANK    336576                 // int[2000]  stable rank of each node
#define WS_PAIRS   344576                 // u32[8192]  packed (a<<16)|b node-id pairs per distinct edge
#define WS_HASH    377344                 // int[32768] hash set
#define WS_PACK    508416                 // u32[313*2000] packed sign bits, layout [word][node]

#define ZERO_BYTES 40128                  // [0, 40128): K + ENC counts
#define ZERO_VEC  (ZERO_BYTES / 16)       // 2508 uint4 zero stores
#define HASH_VEC  (HASH_SZ * 4 / 16)      // 8192 uint4 0xFF stores
#define INIT_TOT  (ZERO_VEC + HASH_VEC)   // 10700
#define FUSE_ITEMS (INIT_TOT + NN * WORDS)        // 636700 work items in blocks 1+
#define FUSE_BLK  ((FUSE_ITEMS + 1023) / 1024)    // 622

// DPP wave64 sum: canonical gfx9 sequence; lane 63 ends with the full wave sum.
// Only used for the err gate (~5 orders of magnitude of tolerance at 0.002).
__device__ __forceinline__ float wave_sum_dpp(float x) {
#define DPPADD(ctrl, rm, bm)                                                     \
  {                                                                              \
    int y_ = __builtin_amdgcn_update_dpp(0, __float_as_int(x), ctrl, rm, bm, false); \
    x = __fadd_rn(x, __int_as_float(y_));                                        \
  }
  DPPADD(0x111, 0xF, 0xF);  // row_shr:1
  DPPADD(0x112, 0xF, 0xF);  // row_shr:2
  DPPADD(0x114, 0xF, 0xE);  // row_shr:4
  DPPADD(0x118, 0xF, 0xC);  // row_shr:8
  DPPADD(0x142, 0xA, 0xF);  // row_bcast:15 -> rows 1,3
  DPPADD(0x143, 0xC, 0xF);  // row_bcast:31 -> rows 2,3
#undef DPPADD
  return x;                  // valid in lane 63
}

// ---------- K1: block 0 = build + pagerank (4 rows/thread, waves 0-7 active);
//            blocks 1+ = workspace init + sign-bit pack (concurrent) ----------
__global__ __launch_bounds__(1024) void fused_pre_kernel(const int* __restrict__ eidx,
                                                         const float* __restrict__ W,
                                                         char* __restrict__ ws) {
  if (blockIdx.x != 0) {
    // ---- init + pack, 1024 threads/block ----
    int t = (int)(blockIdx.x - 1) * 1024 + threadIdx.x;
    if (t < ZERO_VEC) {
      reinterpret_cast<uint4*>(ws)[t] = make_uint4(0u, 0u, 0u, 0u);
      return;
    }
    if (t < INIT_TOT) {
      reinterpret_cast<uint4*>(ws + WS_HASH)[t - ZERO_VEC] =
          make_uint4(0xFFFFFFFFu, 0xFFFFFFFFu, 0xFFFFFFFFu, 0xFFFFFFFFu);
      return;
    }
    int j = t - INIT_TOT;
    if (j >= NN * WORDS) return;
    unsigned int* packed = (unsigned int*)(ws + WS_PACK);
    int w = j / NN;
    int node = j - w * NN;             // consecutive threads -> consecutive nodes, same word
    int d0 = w * 32;
    const float* p = W + (size_t)node * DIM + d0;   // 128B-aligned per-lane chunk
    unsigned int m = 0;
    if (d0 + 32 <= DIM) {
#pragma unroll
      for (int q = 0; q < 8; ++q) {
        float4 v4 = *reinterpret_cast<const float4*>(p + q * 4);
        m |= (__float_as_uint(v4.x) >> 31) << (q * 4);
        m |= (__float_as_uint(v4.y) >> 31) << (q * 4 + 1);
        m |= (__float_as_uint(v4.z) >> 31) << (q * 4 + 2);
        m |= (__float_as_uint(v4.w) >> 31) << (q * 4 + 3);
      }
    } else {
      for (int q = 0; q < DIM - d0; ++q) m |= (__float_as_uint(p[q]) >> 31) << q;
    }
    packed[(size_t)w * NN + node] = m; // coalesced
    return;
  }

  // ---- block 0: build + pagerank ----
  __shared__ unsigned short s_ccol[NE];   // 16 KB  CSR col values
  __shared__ unsigned short s_ced[NE];    // 16 KB  edge ids during build
  __shared__ int s_base[NN + 1];          // 8 KB   CSR row starts
  __shared__ int s_aux[2048];             // degc -> val (f32 alias, in-place)
  __shared__ int s_w[2048];               // rowcnt/scan -> fill counters
  __shared__ float s_wv[2][2048];         // 16 KB  double-buffered val[c]*v[c]
  __shared__ float4 s_red4[2][4];         // err partials (waves 8-15 contribute 0)
  float* s_redf = (float*)s_red4;
  float* s_val = (float*)s_aux;

  int tid = threadIdx.x;
  int wid = tid >> 6, lane = tid & 63;

  for (int i = tid; i < 2048; i += 1024) { s_w[i] = 0; s_aux[i] = 0; }
  for (int i = NN + tid; i < 2048; i += 1024) { s_wv[0][i] = 0.f; s_wv[1][i] = 0.f; }
  __syncthreads();

  // --- count: row counts (s_w) + col in-degree (s_aux) ---
  int er[8], ec[8];
#pragma unroll
  for (int k = 0; k < 8; ++k) {
    int e = tid + k * 1024;
    er[k] = eidx[e];
    ec[k] = eidx[NE + e];
    atomicAdd(&s_w[er[k]], 1);
    atomicAdd(&s_aux[ec[k]], 1);
  }
  __syncthreads();

  // --- inclusive scan of row counts -> base ---
  {
    int n0 = tid, n1 = tid + 1024;
    for (int st = 1; st < 2048; st <<= 1) {
      int v0 = (n0 >= st) ? s_w[n0 - st] : 0;
      int v1 = (n1 >= st) ? s_w[n1 - st] : 0;
      __syncthreads();
      s_w[n0] += v0;
      s_w[n1] += v1;
      __syncthreads();
    }
    if (tid == 0) s_base[0] = 0;
    for (int n = tid; n < NN; n += 1024) s_base[n + 1] = s_w[n];
  }
  __syncthreads();
  for (int i = tid; i < 2048; i += 1024) s_w[i] = 0;   // reuse as fill counters
  __syncthreads();

  // --- fill (atomic, unordered) keeping edge id ---
#pragma unroll
  for (int k = 0; k < 8; ++k) {
    int e = tid + k * 1024;
    int r = er[k];
    int slot = s_base[r] + atomicAdd(&s_w[r], 1);
    s_ccol[slot] = (unsigned short)ec[k];
    s_ced[slot] = (unsigned short)e;
  }
  __syncthreads();

  // --- per-node insertion sort by edge id (stable CSR) + val + wv[0] init ---
  const float p = 0.0005f;              // f32(1.0/2000)
  const float addv = 0.0005f * 0.15f;   // p * f32(1.0-0.85)
  for (int n = tid; n < NN; n += 1024) {
    int s0 = s_base[n], s1 = s_base[n + 1];
    for (int a = s0 + 1; a < s1; ++a) {
      unsigned short ke = s_ced[a], kc = s_ccol[a];
      int b = a - 1;
      while (b >= s0 && s_ced[b] > ke) {
        s_ced[b + 1] = s_ced[b];
        s_ccol[b + 1] = s_ccol[b];
        --b;
      }
      s_ced[b + 1] = ke;
      s_ccol[b + 1] = kc;
    }
    float vv = 0.85f / (float)s_aux[n];   // inf if deg==0: never gathered
    s_val[n] = vv;                        // in-place alias of s_aux[n]
    s_wv[0][n] = __fmul_rn(vv, p);
  }
  __syncthreads();

  // --- hoist per-thread constants: 4 rows/thread for tid<512 (waves 0-7) ---
  // Same per-row arithmetic; only row->thread mapping changes (affects only
  // err's lane pairing, tolerated by the 0.002 gate margin). [verified R14]
  bool own = (tid < 512);
  int r0 = tid, r1 = tid + 512, r2 = tid + 1024, r3 = tid + 1536;
  bool has3 = own && (r3 < NN);
  int b0s = 0, b0e = 0, b1s = 0, b1e = 0, b2s = 0, b2e = 0, b3s = 0, b3e = 0;
  float val0 = 0.f, val1 = 0.f, val2 = 0.f, val3 = 0.f;
  if (own) {
    b0s = s_base[r0]; b0e = s_base[r0 + 1];
    b1s = s_base[r1]; b1e = s_base[r1 + 1];
    b2s = s_base[r2]; b2e = s_base[r2 + 1];
    val0 = s_val[r0]; val1 = s_val[r1]; val2 = s_val[r2];
    if (has3) { b3s = s_base[r3]; b3e = s_base[r3 + 1]; val3 = s_val[r3]; }
  }
  int c0r[REGD], c1r[REGD], c2r[REGD], c3r[REGD];
#pragma unroll
  for (int k = 0; k < REGD; ++k) {
    c0r[k] = (own && b0s + k < b0e) ? (int)s_ccol[min(b0s + k, NE - 1)] : DUMMY;
    c1r[k] = (own && b1s + k < b1e) ? (int)s_ccol[min(b1s + k, NE - 1)] : DUMMY;
    c2r[k] = (own && b2s + k < b2e) ? (int)s_ccol[min(b2s + k, NE - 1)] : DUMMY;
    c3r[k] = (has3 && b3s + k < b3e) ? (int)s_ccol[min(b3s + k, NE - 1)] : DUMMY;
  }
  float vc0 = p, vc1 = p, vc2 = p, vc3 = p;

#define ROW_SUM(CR, BS, BE, VN)                                                \
  {                                                                            \
    float sum = 0.f;                                                           \
    _Pragma("unroll")                                                          \
    for (int k = 0; k < REGD; ++k) sum = __fadd_rn(sum, wv[CR[k]]);            \
    for (int k = (BS) + REGD; k < (BE); ++k) sum = __fadd_rn(sum, wv[s_ccol[k]]); \
    VN = __fadd_rn(sum, addv);                                                 \
  }

  float err = __builtin_inff();
  int it = 0;
  int pb = 0;
  while (it < 100 && err >= 0.002f) {
    const float* wv = s_wv[pb];
    float ep = 0.f;
    float vn0 = vc0, vn1 = vc1, vn2 = vc2, vn3 = vc3;
    if (own) {
      ROW_SUM(c0r, b0s, b0e, vn0); ep += fabsf(__fsub_rn(vn0, vc0));
      ROW_SUM(c1r, b1s, b1e, vn1); ep += fabsf(__fsub_rn(vn1, vc1));
      ROW_SUM(c2r, b2s, b2e, vn2); ep += fabsf(__fsub_rn(vn2, vc2));
      if (has3) { ROW_SUM(c3r, b3s, b3e, vn3); ep += fabsf(__fsub_rn(vn3, vc3)); }
      float* wvn = s_wv[pb ^ 1];         // safe: gathers read s_wv[pb]
      wvn[r0] = __fmul_rn(val0, vn0);
      wvn[r1] = __fmul_rn(val1, vn1);
      wvn[r2] = __fmul_rn(val2, vn2);
      if (has3) wvn[r3] = __fmul_rn(val3, vn3);
    }
    vc0 = vn0; vc1 = vn1; vc2 = vn2; vc3 = vn3;
    float wsum = wave_sum_dpp(ep);       // waves 8-15: exact 0
    if (lane == 63) s_redf[pb * 16 + wid] = wsum;
    __syncthreads();            // wv[pb^1] + s_red[pb] visible; wv[pb] reads done
    float4 q0 = s_red4[pb][0], q1 = s_red4[pb][1], q2 = s_red4[pb][2], q3 = s_red4[pb][3];
    float t = 0.f;
    t += q0.x; t += q0.y; t += q0.z; t += q0.w;
    t += q1.x; t += q1.y; t += q1.z; t += q1.w;
    t += q2.x; t += q2.y; t += q2.z; t += q2.w;   // +0 entries: exact
    t += q3.x; t += q3.y; t += q3.z; t += q3.w;
    err = t;
    pb ^= 1;
    ++it;
  }
#undef ROW_SUM
  float* vout = (float*)(ws + WS_V);
  if (own) {
    vout[r0] = vc0;
    vout[r1] = vc1;
    vout[r2] = vc2;
    if (has3) vout[r3] = vc3;
  }
}

// ---------- K2: blocks 0..31 stable rank; blocks 32..63 dedup (independent) ----------
__global__ __launch_bounds__(256) void rank_dedup_kernel(const int* __restrict__ eidx,
                                                         char* __restrict__ ws) {
  int tid = threadIdx.x;
  if (blockIdx.x < 32) {
    // --- stable rank: LDS-staged, 4-way j-split ---
    const float* v = (const float*)(ws + WS_V);
    int* rnk = (int*)(ws + WS_RANK);
    __shared__ float s_v[NN];
    __shared__ int s_part[4][RBLK];
    for (int j = tid; j < NN; j += 256) s_v[j] = v[j];
    __syncthreads();
    int li = tid & (RBLK - 1);
    int seg = tid >> 6;                  // 0..3
    int i = blockIdx.x * RBLK + li;
    float vi = (i < NN) ? s_v[i] : 0.f;
    const int jper = NN / 4;             // 500
    int j0 = seg * jper, j1 = j0 + jper;
    int r = 0;
    for (int j = j0; j < j1; ++j) {
      float vj = s_v[j];                 // broadcast: conflict-free
      r += ((vj < vi) || (vj == vi && j < i)) ? 1 : 0;
    }
    s_part[seg][li] = r;
    __syncthreads();
    if (tid < RBLK) {
      int i2 = blockIdx.x * RBLK + tid;
      if (i2 < NN)
        rnk[i2] = s_part[0][tid] + s_part[1][tid] + s_part[2][tid] + s_part[3][tid];
    }
  } else {
    // --- dedup via hash set; pairs carry NODE IDS (rank translation in encpop) ---
    int* hash = (int*)(ws + WS_HASH);
    unsigned int* pairs = (unsigned int*)(ws + WS_PAIRS);
    int* Kp = (int*)(ws + WS_K);
    int e = (int)(blockIdx.x - 32) * 256 + tid;
    int r = eidx[e], c = eidx[NE + e];
    int a = min(r, c), b = max(r, c);
    int key = a * NN + b;
    unsigned int h = ((unsigned int)key * 2654435761u) >> 17;
    for (;;) {
      h &= (HASH_SZ - 1);
      int old = atomicCAS(&hash[h], -1, key);
      if (old == -1) {                   // this edge owns the distinct key
        int idx = atomicAdd(Kp, 1);
        pairs[idx] = ((unsigned int)a << 16) | (unsigned int)b;
        return;
      }
      if (old == key) return;            // duplicate
      ++h;
    }
  }
}

// ---------- K3: per-dim xor-bit counts; node->rank translation at staging ----------
__global__ __launch_bounds__(256) void encpop_kernel(char* __restrict__ ws) {
  const unsigned int* packed = (const unsigned int*)(ws + WS_PACK);
  const unsigned int* pairs = (const unsigned int*)(ws + WS_PAIRS);
  const int* Kp = (const int*)(ws + WS_K);
  const int* rnk_g = (const int*)(ws + WS_RANK);
  int* enc_int = (int*)(ws + WS_ENC);
  __shared__ unsigned short s_rnk[NN]; // node -> rank
  __shared__ unsigned int s_col[NN];   // node -> this word's bits of W-row rank[node]
  __shared__ int s_part[4][32];
  int w = blockIdx.x;
  int tid = threadIdx.x;
  int wid = tid >> 6, lane = tid & 63;
  for (int i = tid; i < NN; i += 256) s_rnk[i] = (unsigned short)rnk_g[i];
  __syncthreads();
  for (int i = tid; i < NN; i += 256)
    s_col[i] = packed[(size_t)w * NN + s_rnk[i]];   // L2-resident gather
  __syncthreads();
  int K = *Kp;
  const int per = NE / ECH;            // 1024
  int e0 = blockIdx.y * per;
  int cnt[32];
#pragma unroll
  for (int b = 0; b < 32; ++b) cnt[b] = 0;
  for (int e = e0 + tid; e < e0 + per; e += 256) {   // uniform trip count: ballot-safe
    unsigned int x = 0;
    if (e < K) {
      unsigned int pk = pairs[e];
      x = s_col[pk >> 16] ^ s_col[pk & 0xffffu];
    }
#pragma unroll
    for (int b = 0; b < 32; ++b)
      cnt[b] += (int)__popcll(__ballot(x & (1u << b)));   // uniform per wave
  }
  if (lane == 0) {
#pragma unroll
    for (int b = 0; b < 32; ++b) s_part[wid][b] = cnt[b];
  }
  __syncthreads();
  if (tid < 32) {
    int tot = s_part[0][tid] + s_part[1][tid] + s_part[2][tid] + s_part[3][tid];
    if (tot) atomicAdd(&enc_int[w * 32 + tid], tot);   // exact integer accumulation
  }
}

// ---------- K4: out[c] = sum_d (K - 2*cnt[d]) * Wc[c][d] ----------
__global__ __launch_bounds__(256) void out_kernel(const float* __restrict__ Wc,
                                                  char* __restrict__ ws,
                                                  float* __restrict__ out) {
  const int* enc_int = (const int*)(ws + WS_ENC);
  int K = *(const int*)(ws + WS_K);
  __shared__ float red[4];
  int c = blockIdx.x;
  float s = 0.f;
  for (int d = threadIdx.x; d < DIM; d += 256)
    s += (float)(K - 2 * enc_int[d]) * Wc[c * DIM + d];
  for (int o = 32; o > 0; o >>= 1) s += __shfl_down(s, o, 64);
  if ((threadIdx.x & 63) == 0) red[threadIdx.x >> 6] = s;
  __syncthreads();
  if (threadIdx.x == 0) out[c] = red[0] + red[1] + red[2] + red[3];
}

extern "C" void kernel_launch(void* const* d_in, const int* in_sizes, int n_in,
                              void* d_out, int out_size, void* d_ws, size_t ws_size,
                              hipStream_t stream) {
  const int* eidx = (const int*)d_in[0];        // edge_index int32 [2, 8192]
  const float* Wn = (const float*)d_in[1];      // node_ids_weight f32 [2000, 10000]
  const float* Wc = (const float*)d_in[2];      // classify_weight f32 [10, 10000]
  float* out = (float*)d_out;
  char* ws = (char*)d_ws;

  fused_pre_kernel<<<FUSE_BLK + 1, 1024, 0, stream>>>(eidx, Wn, ws);
  rank_dedup_kernel<<<64, 256, 0, stream>>>(eidx, ws);
  encpop_kernel<<<dim3(WORDS, ECH), 256, 0, stream>>>(ws);
  out_kernel<<<NCLS, 256, 0, stream>>>(Wc, ws, out);
}